// Round 5
// baseline (240.212 us; speedup 1.0000x reference)
//
#include <hip/hip_runtime.h>

typedef unsigned short u16;
typedef unsigned int   u32;

using bf16x8 = __attribute__((ext_vector_type(8))) short;
using f32x4  = __attribute__((ext_vector_type(4))) float;

#define MFMA16(a, b, c) __builtin_amdgcn_mfma_f32_16x16x32_bf16((a), (b), (c), 0, 0, 0)

__device__ __forceinline__ u16 f2bf(float f) {
  union { float f; u32 u; } x; x.f = f;
  u32 r = x.u + 0x7fffu + ((x.u >> 16) & 1u);
  return (u16)(r >> 16);
}

__device__ __forceinline__ float bf2f(u16 v) {
  union { u32 u; float f; } x; x.u = ((u32)v) << 16;
  return x.f;
}

// packed f32x2 -> bf16x2 (RNE), single instruction; no builtin on gfx950
__device__ __forceinline__ u32 cvtpk(float lo, float hi) {
  u32 r;
  asm("v_cvt_pk_bf16_f32 %0, %1, %2" : "=v"(r) : "v"(lo), "v"(hi));
  return r;
}

// async global->LDS, 16B per lane; LDS dest must be wave-uniform base (HW adds lane*16)
__device__ __forceinline__ void gl2lds16(const void* g, void* l) {
  __builtin_amdgcn_global_load_lds(
      (const __attribute__((address_space(1))) u32*)g,
      (__attribute__((address_space(3))) u32*)l, 16, 0, 0);
}

// ---------------- fp32 -> bf16 elementwise (8 elems/thread) ----------------
__global__ __launch_bounds__(256) void cvt_f32_bf16(const float* __restrict__ in,
                                                    u16* __restrict__ out, long n8) {
  long i = (long)blockIdx.x * 256 + threadIdx.x;
  if (i >= n8) return;
  const float4* p = (const float4*)(in + i * 8);
  float4 a = p[0], b = p[1];
  uint4 pk;
  pk.x = cvtpk(a.x, a.y);
  pk.y = cvtpk(a.z, a.w);
  pk.z = cvtpk(b.x, b.y);
  pk.w = cvtpk(b.z, b.w);
  *(uint4*)(out + i * 8) = pk;
}

// ---------------- weight convert + transpose: W[K][N] f32 -> Wt[N][K] bf16 --
__global__ __launch_bounds__(256) void wt_cvt_t(const float* __restrict__ W,
                                                u16* __restrict__ Wt, int K, int N) {
  __shared__ u16 t[64][66];
  int tilesN = N >> 6;
  int k0 = ((int)blockIdx.x / tilesN) << 6;
  int n0 = ((int)blockIdx.x % tilesN) << 6;
  int tid = threadIdx.x;
  int c4 = (tid & 15) * 4, r16 = tid >> 4;
#pragma unroll
  for (int p = 0; p < 4; ++p) {
    int row = r16 + p * 16;
    float4 f = *(const float4*)(W + (size_t)(k0 + row) * N + n0 + c4);
    t[row][c4 + 0] = f2bf(f.x);
    t[row][c4 + 1] = f2bf(f.y);
    t[row][c4 + 2] = f2bf(f.z);
    t[row][c4 + 3] = f2bf(f.w);
  }
  __syncthreads();
  int c8 = (tid & 7) * 8, r32 = tid >> 3;
#pragma unroll
  for (int p = 0; p < 2; ++p) {
    int n = r32 + p * 32;
    u16 tmp[8] __attribute__((aligned(16)));
#pragma unroll
    for (int e = 0; e < 8; ++e) tmp[e] = t[c8 + e][n];
    *(uint4*)(Wt + (size_t)(n0 + n) * K + k0 + c8) = *(uint4*)tmp;
  }
}

// ---------------- MFMA GEMM: C[M][N] = A[M][K] * Bt[N][K]^T + bias ---------
// 128x128 tile, BK=64, 8 waves (2m x 4n, per-wave 64x32), XOR-swizzled LDS,
// DOUBLE-BUFFERED 2-phase K-loop (stage t+1 || compute t, one barrier/step),
// pure global_load_lds staging, XCD M-chunked block swizzle.
// MODE 0: relu, write bf16
// MODE 2: write bf16 permuted to [B][H][L][64] (q-proj)
// MODE 4: like 2, plus transposed write [BH][64][512] (vs-proj, fused transpose)
// MODE 3: out = acc + bias + bf2f(add0b[m][n]) + add1[m&511][n], f32 (out-proj)
template <int MODE>
__global__ __launch_bounds__(512) void gemm_bf16(
    const u16* __restrict__ A, const u16* __restrict__ Bt,
    const float* __restrict__ bias, u16* __restrict__ outb, float* __restrict__ outf,
    u16* __restrict__ outt, const u16* __restrict__ add0b,
    const float* __restrict__ add1, int M, int N, int K) {
  __shared__ u16 sA[2][128 * 64];
  __shared__ u16 sB[2][128 * 64];
  int tilesN = N >> 7;
  // bijective XCD-chunked swizzle: XCD x owns a contiguous tm range (A stays L2-hot)
  int nwg = (int)gridDim.x;
  int cpx = nwg >> 3;
  int orig = (int)blockIdx.x;
  int wg = (orig & 7) * cpx + (orig >> 3);
  int tm = wg / tilesN, tn = wg % tilesN;
  int m0 = tm << 7, n0 = tn << 7;
  int tid = threadIdx.x, w = tid >> 6, l = tid & 63;
  int wm = (w >> 2) << 6, wn = (w & 3) << 5;
  int c16 = l & 15, hi = l >> 4, g16 = hi * 16;

  f32x4 acc[4][2];
#pragma unroll
  for (int i = 0; i < 4; ++i)
#pragma unroll
    for (int j = 0; j < 2; ++j) acc[i][j] = (f32x4){0.f, 0.f, 0.f, 0.f};

  // stage K-tile kt into buffer buf (512 lanes x 16B x 2 parts = 16KB per array)
  auto STAGE = [&](int kt, int buf) {
    const u16* Ab = A + (size_t)m0 * K + kt * 64;
    const u16* Bb = Bt + (size_t)n0 * K + kt * 64;
#pragma unroll
    for (int p = 0; p < 2; ++p) {
      int lin = p * 8192 + tid * 16;          // linear byte in 16KB tile
      int row = lin >> 7;                     // 128B rows
      int cb = (lin & 127) ^ ((row & 7) << 4);  // pre-swizzled source column
      int base = lin & ~1023;                 // wave-uniform LDS chunk base
      gl2lds16(Ab + (size_t)row * K + (cb >> 1), (char*)sA[buf] + base);
      gl2lds16(Bb + (size_t)row * K + (cb >> 1), (char*)sB[buf] + base);
    }
  };

  auto COMPUTE = [&](int buf) {
#pragma unroll
    for (int kk = 0; kk < 2; ++kk) {
      bf16x8 af[4], bfr[2];
#pragma unroll
      for (int i = 0; i < 4; ++i) {
        int ar = wm + i * 16 + c16;
        af[i] = *(const bf16x8*)((const char*)sA[buf] + ar * 128 +
                                 ((kk * 64 + g16) ^ ((ar & 7) << 4)));
      }
#pragma unroll
      for (int j = 0; j < 2; ++j) {
        int br = wn + j * 16 + c16;
        bfr[j] = *(const bf16x8*)((const char*)sB[buf] + br * 128 +
                                  ((kk * 64 + g16) ^ ((br & 7) << 4)));
      }
#pragma unroll
      for (int i = 0; i < 4; ++i)
#pragma unroll
        for (int j = 0; j < 2; ++j) acc[i][j] = MFMA16(af[i], bfr[j], acc[i][j]);
    }
  };

  int nk = K >> 6;
  STAGE(0, 0);
  __syncthreads();  // implicit vmcnt(0) drain: buf0 ready
  int cur = 0;
  for (int kt = 0; kt < nk - 1; ++kt) {
    STAGE(kt + 1, cur ^ 1);  // prefetch next tile (latency hides under compute)
    COMPUTE(cur);
    __syncthreads();  // drains prefetch + all waves done reading cur
    cur ^= 1;
  }
  COMPUTE(cur);

#pragma unroll
  for (int i = 0; i < 4; ++i) {
#pragma unroll
    for (int j = 0; j < 2; ++j) {
      float vv[4];
      int gn = n0 + wn + j * 16 + c16;
#pragma unroll
      for (int r = 0; r < 4; ++r) vv[r] = acc[i][j][r] + bias[gn];
      int gm0 = m0 + wm + i * 16 + hi * 4;
      if (MODE == 0) {
#pragma unroll
        for (int r = 0; r < 4; ++r)
          outb[(size_t)(gm0 + r) * N + gn] = f2bf(fmaxf(vv[r], 0.f));
      } else if (MODE == 2 || MODE == 4) {
        int hh = gn >> 6, dk = gn & 63, bb2 = gm0 >> 9, ll2 = gm0 & 511;
#pragma unroll
        for (int r = 0; r < 4; ++r)
          outb[(((size_t)bb2 * 16 + hh) * 512 + ll2 + r) * 64 + dk] = f2bf(vv[r]);
        if (MODE == 4) {
          uint2 tw;
          tw.x = cvtpk(vv[0], vv[1]);
          tw.y = cvtpk(vv[2], vv[3]);
          *(uint2*)(outt + (((size_t)bb2 * 16 + hh) * 64 + dk) * 512 + ll2) = tw;
        }
      } else {  // MODE 3
#pragma unroll
        for (int r = 0; r < 4; ++r) {
          int gm = gm0 + r;
          float v = vv[r] + bf2f(add0b[(size_t)gm * N + gn]) +
                    add1[(size_t)(gm & 511) * N + gn];
          outf[(size_t)gm * N + gn] = v;
        }
      }
    }
  }
}

// ---------------- fused attention: swapped-QK^T + swapped-PV ---------------
__global__ __launch_bounds__(512) void attn_kernel(const u16* __restrict__ q,
                                                   const u16* __restrict__ kv,
                                                   const u16* __restrict__ kvT,
                                                   u16* __restrict__ ctx) {
  __shared__ u16 sK[2][4096];   // [64 keys][64 dk], 128B rows, XOR swizzle
  __shared__ u16 sVT[2][4096];  // [64 dv][64 keys]
  __shared__ u16 sP[8192];      // Q staging (128x64), then per-wave P (16x64 each)

  int orig = (int)blockIdx.x;
  int r = (orig & 7) * 128 + (orig >> 3);
  int bh = r >> 2, qt = r & 3;
  int b = bh >> 4, h = bh & 15;
  int tid = threadIdx.x, w = tid >> 6, l = tid & 63;
  int c16 = l & 15, hi = l >> 4, g16 = hi * 16;
  int swzq = (c16 & 7) << 4;

  const u16* qbase = q + (size_t)bh * 32768 + (size_t)qt * 8192;
#pragma unroll
  for (int j = 0; j < 2; ++j) {
    int chunk = w * 2 + j;
    int lin = chunk * 1024 + l * 16;
    int row = lin >> 7;
    int cb = (lin & 127) ^ ((row & 7) << 4);
    gl2lds16(qbase + (size_t)row * 64 + (cb >> 1), (char*)sP + chunk * 1024);
  }
  {
    const u16* kb = kv + (size_t)bh * 32768;
    const u16* vb = kvT + (size_t)bh * 32768;
    int lin = w * 1024 + l * 16;
    int row = lin >> 7;
    int cb = (lin & 127) ^ ((row & 7) << 4);
    gl2lds16(kb + (size_t)row * 64 + (cb >> 1), (char*)sK[0] + w * 1024);
    gl2lds16(vb + (size_t)row * 512 + (cb >> 1), (char*)sVT[0] + w * 1024);
  }
  __syncthreads();

  const char* sQrow = (const char*)sP + (w * 16 + c16) * 128;
  bf16x8 qf0 = *(const bf16x8*)(sQrow + ((0 + g16) ^ swzq));
  bf16x8 qf1 = *(const bf16x8*)(sQrow + ((64 + g16) ^ swzq));

  char* sPw = (char*)sP + w * 2048;
  f32x4 of[4];
#pragma unroll
  for (int n = 0; n < 4; ++n) of[n] = (f32x4){0.f, 0.f, 0.f, 0.f};
  float m_run = -1e30f, l_run = 0.f;

  for (int c = 0; c < 8; ++c) {
    int cur = c & 1;
    if (c < 7) {
      const u16* kb = kv + (size_t)bh * 32768 + (size_t)(c + 1) * 4096;
      const u16* vb = kvT + (size_t)bh * 32768 + (c + 1) * 64;
      int lin = w * 1024 + l * 16;
      int row = lin >> 7;
      int cb = (lin & 127) ^ ((row & 7) << 4);
      gl2lds16(kb + (size_t)row * 64 + (cb >> 1), (char*)sK[cur ^ 1] + w * 1024);
      gl2lds16(vb + (size_t)row * 512 + (cb >> 1), (char*)sVT[cur ^ 1] + w * 1024);
    }
    const char* kbuf = (const char*)sK[cur];
    const char* vtbuf = (const char*)sVT[cur];

    f32x4 sf[4];
#pragma unroll
    for (int n = 0; n < 4; ++n) {
      const char* krow = kbuf + (n * 16 + c16) * 128;
      bf16x8 k0 = *(const bf16x8*)(krow + (g16 ^ swzq));
      bf16x8 k1 = *(const bf16x8*)(krow + ((64 + g16) ^ swzq));
      f32x4 z = (f32x4){0.f, 0.f, 0.f, 0.f};
      z = MFMA16(k0, qf0, z);
      z = MFMA16(k1, qf1, z);
      sf[n] = z;
    }

    float pmax = -1e30f;
#pragma unroll
    for (int n = 0; n < 4; ++n)
#pragma unroll
      for (int rr = 0; rr < 4; ++rr) {
        sf[n][rr] *= 0.125f;
        pmax = fmaxf(pmax, sf[n][rr]);
      }
    pmax = fmaxf(pmax, __shfl_xor(pmax, 16));
    pmax = fmaxf(pmax, __shfl_xor(pmax, 32));
    float mnew = fmaxf(m_run, pmax);
    float corr = __expf(m_run - mnew);
    float psum = 0.f;
#pragma unroll
    for (int n = 0; n < 4; ++n)
#pragma unroll
      for (int rr = 0; rr < 4; ++rr) {
        float p = __expf(sf[n][rr] - mnew);
        sf[n][rr] = p;
        psum += p;
      }
    psum += __shfl_xor(psum, 16);
    psum += __shfl_xor(psum, 32);
    l_run = l_run * corr + psum;
    m_run = mnew;
#pragma unroll
    for (int n = 0; n < 4; ++n)
#pragma unroll
      for (int rr = 0; rr < 4; ++rr) of[n][rr] *= corr;

#pragma unroll
    for (int n = 0; n < 4; ++n) {
      uint2 pw;
      pw.x = cvtpk(sf[n][0], sf[n][1]);
      pw.y = cvtpk(sf[n][2], sf[n][3]);
      *(uint2*)(sPw + c16 * 128 + ((n * 32 + hi * 8) ^ swzq)) = pw;
    }

    bf16x8 pf0 = *(const bf16x8*)(sPw + c16 * 128 + (g16 ^ swzq));
    bf16x8 pf1 = *(const bf16x8*)(sPw + c16 * 128 + ((64 + g16) ^ swzq));
#pragma unroll
    for (int n = 0; n < 4; ++n) {
      const char* vrow = vtbuf + (n * 16 + c16) * 128;
      bf16x8 v0 = *(const bf16x8*)(vrow + (g16 ^ swzq));
      bf16x8 v1 = *(const bf16x8*)(vrow + ((64 + g16) ^ swzq));
      of[n] = MFMA16(v0, pf0, of[n]);
      of[n] = MFMA16(v1, pf1, of[n]);
    }
    __syncthreads();
  }

  float inv = 1.0f / l_run;
  int grow = qt * 128 + w * 16 + c16;
  u16* obase = ctx + (size_t)(b * 512 + grow) * 1024 + h * 64;
#pragma unroll
  for (int n = 0; n < 4; ++n) {
    uint2 ow;
    ow.x = cvtpk(of[n][0] * inv, of[n][1] * inv);
    ow.y = cvtpk(of[n][2] * inv, of[n][3] * inv);
    *(uint2*)(obase + n * 16 + hi * 4) = ow;
  }
}

// ---------------- in-place LayerNorm over D=1024 ---------------------------
__global__ __launch_bounds__(256) void ln_kernel(float* __restrict__ x,
                                                 const float* __restrict__ gamma,
                                                 const float* __restrict__ beta) {
  __shared__ float red[4];
  __shared__ float red2[4];
  int row = blockIdx.x, tid = threadIdx.x;
  float4 v = *(float4*)(x + (size_t)row * 1024 + tid * 4);
  float s = v.x + v.y + v.z + v.w;
#pragma unroll
  for (int d = 1; d < 64; d <<= 1) s += __shfl_xor(s, d);
  if ((tid & 63) == 0) red[tid >> 6] = s;
  __syncthreads();
  float mu = (red[0] + red[1] + red[2] + red[3]) * (1.0f / 1024.0f);
  float d0 = v.x - mu, d1 = v.y - mu, d2 = v.z - mu, d3 = v.w - mu;
  float qq = d0 * d0 + d1 * d1 + d2 * d2 + d3 * d3;
#pragma unroll
  for (int d = 1; d < 64; d <<= 1) qq += __shfl_xor(qq, d);
  if ((tid & 63) == 0) red2[tid >> 6] = qq;
  __syncthreads();
  float var = (red2[0] + red2[1] + red2[2] + red2[3]) * (1.0f / 1024.0f);
  float rstd = rsqrtf(var + 1e-6f);
  float4 g = *(const float4*)(gamma + tid * 4);
  float4 bb = *(const float4*)(beta + tid * 4);
  v.x = g.x * d0 * rstd + bb.x;
  v.y = g.y * d1 * rstd + bb.y;
  v.z = g.z * d2 * rstd + bb.z;
  v.w = g.w * d3 * rstd + bb.w;
  *(float4*)(x + (size_t)row * 1024 + tid * 4) = v;
}

extern "C" void kernel_launch(void* const* d_in, const int* in_sizes, int n_in,
                              void* d_out, int out_size, void* d_ws, size_t ws_size,
                              hipStream_t stream) {
  (void)in_sizes; (void)n_in; (void)out_size; (void)ws_size;
  const float* v_in  = (const float*)d_in[0];
  const float* s_in  = (const float*)d_in[1];
  const float* W_lv  = (const float*)d_in[2];
  const float* b_lv  = (const float*)d_in[3];
  const float* W_ls  = (const float*)d_in[4];
  const float* b_ls  = (const float*)d_in[5];
  const float* pos_v = (const float*)d_in[6];
  // d_in[7] = pos_s (unused), d_in[10]/[11] = W_k/b_k (discarded in ref)
  const float* W_q   = (const float*)d_in[8];
  const float* b_q   = (const float*)d_in[9];
  const float* W_v   = (const float*)d_in[12];
  const float* b_v   = (const float*)d_in[13];
  const float* W_p   = (const float*)d_in[14];
  const float* b_p   = (const float*)d_in[15];
  const float* gamma = (const float*)d_in[16];
  const float* beta  = (const float*)d_in[17];
  float* out = (float*)d_out;

  char* ws = (char*)d_ws;
  size_t off = 0;
  auto alloc = [&](size_t bytes) {
    char* p = ws + off;
    off += (bytes + 255) & ~(size_t)255;
    return p;
  };
  u16* v_bf     = (u16*)alloc(33554432);   // [8192][2048] bf16
  u16* s_bf     = (u16*)alloc(12582912);   // [8192][768]
  u16* Wlv_t    = (u16*)alloc(4194304);    // [1024][2048] bf16
  u16* Wls_t    = (u16*)alloc(1572864);    // [1024][768]
  u16* Wq_t     = (u16*)alloc(2097152);    // [1024][1024]
  u16* Wv_t     = (u16*)alloc(2097152);
  u16* Wp_t     = (u16*)alloc(2097152);
  u16* vproj_bf = (u16*)alloc(16777216);   // [8192][1024] (also the residual, bf16)
  u16* sproj_bf = (u16*)alloc(16777216);
  u16* q_bf     = (u16*)alloc(16777216);   // [BH][512][64]
  u16* vs_bf    = (u16*)alloc(16777216);   // [BH][512][64]
  u16* vsT_bf   = (u16*)alloc(16777216);   // [BH][64][512]
  u16* ctx_bf   = (u16*)alloc(16777216);   // [8192][1024]

  cvt_f32_bf16<<<8192, 256, 0, stream>>>(v_in, v_bf, 2097152);
  cvt_f32_bf16<<<3072, 256, 0, stream>>>(s_in, s_bf, 786432);
  wt_cvt_t<<<512, 256, 0, stream>>>(W_lv, Wlv_t, 2048, 1024);
  wt_cvt_t<<<192, 256, 0, stream>>>(W_ls, Wls_t, 768, 1024);
  wt_cvt_t<<<256, 256, 0, stream>>>(W_q, Wq_t, 1024, 1024);
  wt_cvt_t<<<256, 256, 0, stream>>>(W_v, Wv_t, 1024, 1024);
  wt_cvt_t<<<256, 256, 0, stream>>>(W_p, Wp_t, 1024, 1024);

  // v-proj + s-proj (bf16 A via gl2lds, 2-phase double-buffered)
  gemm_bf16<0><<<512, 512, 0, stream>>>(v_bf, Wlv_t, b_lv, vproj_bf, nullptr,
                                        nullptr, nullptr, nullptr, 8192, 1024, 2048);
  gemm_bf16<0><<<512, 512, 0, stream>>>(s_bf, Wls_t, b_ls, sproj_bf, nullptr,
                                        nullptr, nullptr, nullptr, 8192, 1024, 768);
  // q-proj
  gemm_bf16<2><<<512, 512, 0, stream>>>(vproj_bf, Wq_t, b_q, q_bf, nullptr,
                                        nullptr, nullptr, nullptr, 8192, 1024, 1024);
  // vs-proj with fused transpose (writes vs and vs^T)
  gemm_bf16<4><<<512, 512, 0, stream>>>(sproj_bf, Wv_t, b_v, vs_bf, nullptr,
                                        vsT_bf, nullptr, nullptr, 8192, 1024, 1024);
  attn_kernel<<<1024, 512, 0, stream>>>(q_bf, vs_bf, vsT_bf, ctx_bf);
  // out-proj + residual(bf16) + pos_v
  gemm_bf16<3><<<512, 512, 0, stream>>>(ctx_bf, Wp_t, b_p, nullptr, out,
                                        nullptr, vproj_bf, pos_v, 8192, 1024, 1024);
  ln_kernel<<<8192, 256, 0, stream>>>(out, gamma, beta);
}

// Round 6
// 223.903 us; speedup vs baseline: 1.0728x; 1.0728x over previous
//
#include <hip/hip_runtime.h>

typedef unsigned short u16;
typedef unsigned int   u32;

using bf16x8 = __attribute__((ext_vector_type(8))) short;
using f32x4  = __attribute__((ext_vector_type(4))) float;

#define MFMA16(a, b, c) __builtin_amdgcn_mfma_f32_16x16x32_bf16((a), (b), (c), 0, 0, 0)

__device__ __forceinline__ u16 f2bf(float f) {
  union { float f; u32 u; } x; x.f = f;
  u32 r = x.u + 0x7fffu + ((x.u >> 16) & 1u);
  return (u16)(r >> 16);
}

__device__ __forceinline__ float bf2f(u16 v) {
  union { u32 u; float f; } x; x.u = ((u32)v) << 16;
  return x.f;
}

// packed f32x2 -> bf16x2 (RNE), single instruction; no builtin on gfx950
__device__ __forceinline__ u32 cvtpk(float lo, float hi) {
  u32 r;
  asm("v_cvt_pk_bf16_f32 %0, %1, %2" : "=v"(r) : "v"(lo), "v"(hi));
  return r;
}

// async global->LDS, 16B per lane; LDS dest must be wave-uniform base (HW adds lane*16)
__device__ __forceinline__ void gl2lds16(const void* g, void* l) {
  __builtin_amdgcn_global_load_lds(
      (const __attribute__((address_space(1))) u32*)g,
      (__attribute__((address_space(3))) u32*)l, 16, 0, 0);
}

// ---------------- fp32 -> bf16 elementwise (8 elems/thread) ----------------
__global__ __launch_bounds__(256) void cvt_f32_bf16(const float* __restrict__ in,
                                                    u16* __restrict__ out, long n8) {
  long i = (long)blockIdx.x * 256 + threadIdx.x;
  if (i >= n8) return;
  const float4* p = (const float4*)(in + i * 8);
  float4 a = p[0], b = p[1];
  uint4 pk;
  pk.x = cvtpk(a.x, a.y);
  pk.y = cvtpk(a.z, a.w);
  pk.z = cvtpk(b.x, b.y);
  pk.w = cvtpk(b.z, b.w);
  *(uint4*)(out + i * 8) = pk;
}

// ---------------- weight convert + transpose: W[K][N] f32 -> Wt[N][K] bf16 --
__global__ __launch_bounds__(256) void wt_cvt_t(const float* __restrict__ W,
                                                u16* __restrict__ Wt, int K, int N) {
  __shared__ u16 t[64][66];
  int tilesN = N >> 6;
  int k0 = ((int)blockIdx.x / tilesN) << 6;
  int n0 = ((int)blockIdx.x % tilesN) << 6;
  int tid = threadIdx.x;
  int c4 = (tid & 15) * 4, r16 = tid >> 4;
#pragma unroll
  for (int p = 0; p < 4; ++p) {
    int row = r16 + p * 16;
    float4 f = *(const float4*)(W + (size_t)(k0 + row) * N + n0 + c4);
    t[row][c4 + 0] = f2bf(f.x);
    t[row][c4 + 1] = f2bf(f.y);
    t[row][c4 + 2] = f2bf(f.z);
    t[row][c4 + 3] = f2bf(f.w);
  }
  __syncthreads();
  int c8 = (tid & 7) * 8, r32 = tid >> 3;
#pragma unroll
  for (int p = 0; p < 2; ++p) {
    int n = r32 + p * 32;
    u16 tmp[8] __attribute__((aligned(16)));
#pragma unroll
    for (int e = 0; e < 8; ++e) tmp[e] = t[c8 + e][n];
    *(uint4*)(Wt + (size_t)(n0 + n) * K + k0 + c8) = *(uint4*)tmp;
  }
}

// ---------------- MFMA GEMM: C[M][N] = A[M][K] * Bt[N][K]^T + bias ---------
// 128x128 tile, BK=64, 8 waves (2m x 4n, per-wave 64x32), XOR-swizzled LDS,
// double-buffered K-loop with COUNTED vmcnt across raw s_barriers (T3/T4):
//   STAGE(kt+1) ; vmcnt(4) ; s_barrier ; COMPUTE(kt) ; s_barrier
// so next-tile loads stay in flight across the barrier (no vmcnt(0) drain).
// MODE 0: relu, write bf16
// MODE 2: write bf16 permuted to [B][H][L][64] (q-proj)
// MODE 4: like 2, plus transposed write [BH][64][512] (vs-proj, fused transpose)
// MODE 3: out = acc + bias + bf2f(add0b[m][n]) + add1[m&511][n], f32 (out-proj)
template <int MODE>
__global__ __launch_bounds__(512) void gemm_bf16(
    const u16* __restrict__ A, const u16* __restrict__ Bt,
    const float* __restrict__ bias, u16* __restrict__ outb, float* __restrict__ outf,
    u16* __restrict__ outt, const u16* __restrict__ add0b,
    const float* __restrict__ add1, int M, int N, int K) {
  __shared__ u16 sA[2][128 * 64];
  __shared__ u16 sB[2][128 * 64];
  int tilesN = N >> 7;
  // bijective XCD-chunked swizzle: XCD x owns a contiguous tm range (A stays L2-hot)
  int nwg = (int)gridDim.x;
  int cpx = nwg >> 3;
  int orig = (int)blockIdx.x;
  int wg = (orig & 7) * cpx + (orig >> 3);
  int tm = wg / tilesN, tn = wg % tilesN;
  int m0 = tm << 7, n0 = tn << 7;
  int tid = threadIdx.x, w = tid >> 6, l = tid & 63;
  int wm = (w >> 2) << 6, wn = (w & 3) << 5;
  int c16 = l & 15, hi = l >> 4, g16 = hi * 16;

  f32x4 acc[4][2];
#pragma unroll
  for (int i = 0; i < 4; ++i)
#pragma unroll
    for (int j = 0; j < 2; ++j) acc[i][j] = (f32x4){0.f, 0.f, 0.f, 0.f};

  // stage K-tile kt into buffer buf: 4 gl2lds per wave (vmcnt += 4)
  auto STAGE = [&](int kt, int buf) {
    const u16* Ab = A + (size_t)m0 * K + kt * 64;
    const u16* Bb = Bt + (size_t)n0 * K + kt * 64;
#pragma unroll
    for (int p = 0; p < 2; ++p) {
      int lin = p * 8192 + tid * 16;          // linear byte in 16KB tile
      int row = lin >> 7;                     // 128B rows
      int cb = (lin & 127) ^ ((row & 7) << 4);  // pre-swizzled source column
      int base = lin & ~1023;                 // wave-uniform LDS chunk base
      gl2lds16(Ab + (size_t)row * K + (cb >> 1), (char*)sA[buf] + base);
      gl2lds16(Bb + (size_t)row * K + (cb >> 1), (char*)sB[buf] + base);
    }
  };

  auto COMPUTE = [&](int buf) {
#pragma unroll
    for (int kk = 0; kk < 2; ++kk) {
      bf16x8 af[4], bfr[2];
#pragma unroll
      for (int i = 0; i < 4; ++i) {
        int ar = wm + i * 16 + c16;
        af[i] = *(const bf16x8*)((const char*)sA[buf] + ar * 128 +
                                 ((kk * 64 + g16) ^ ((ar & 7) << 4)));
      }
#pragma unroll
      for (int j = 0; j < 2; ++j) {
        int br = wn + j * 16 + c16;
        bfr[j] = *(const bf16x8*)((const char*)sB[buf] + br * 128 +
                                  ((kk * 64 + g16) ^ ((br & 7) << 4)));
      }
#pragma unroll
      for (int i = 0; i < 4; ++i)
#pragma unroll
        for (int j = 0; j < 2; ++j) acc[i][j] = MFMA16(af[i], bfr[j], acc[i][j]);
    }
  };

  int nk = K >> 6;
  STAGE(0, 0);
  int cur = 0;
  for (int kt = 0; kt < nk; ++kt) {
    if (kt + 1 < nk) {
      STAGE(kt + 1, cur ^ 1);  // 4 more loads in flight (8 total)
      __builtin_amdgcn_sched_barrier(0);
      asm volatile("s_waitcnt vmcnt(4)" ::: "memory");  // tile kt landed; kt+1 in flight
    } else {
      asm volatile("s_waitcnt vmcnt(0)" ::: "memory");  // final tile: full drain
    }
    __builtin_amdgcn_s_barrier();      // all waves: buf[cur] published
    __builtin_amdgcn_sched_barrier(0); // no ds_read hoisting above the barrier
    COMPUTE(cur);
    __builtin_amdgcn_sched_barrier(0);
    __builtin_amdgcn_s_barrier();      // all waves done reading buf[cur] before re-stage
    cur ^= 1;
  }

#pragma unroll
  for (int i = 0; i < 4; ++i) {
#pragma unroll
    for (int j = 0; j < 2; ++j) {
      float vv[4];
      int gn = n0 + wn + j * 16 + c16;
#pragma unroll
      for (int r = 0; r < 4; ++r) vv[r] = acc[i][j][r] + bias[gn];
      int gm0 = m0 + wm + i * 16 + hi * 4;
      if (MODE == 0) {
#pragma unroll
        for (int r = 0; r < 4; ++r)
          outb[(size_t)(gm0 + r) * N + gn] = f2bf(fmaxf(vv[r], 0.f));
      } else if (MODE == 2 || MODE == 4) {
        int hh = gn >> 6, dk = gn & 63, bb2 = gm0 >> 9, ll2 = gm0 & 511;
#pragma unroll
        for (int r = 0; r < 4; ++r)
          outb[(((size_t)bb2 * 16 + hh) * 512 + ll2 + r) * 64 + dk] = f2bf(vv[r]);
        if (MODE == 4) {
          uint2 tw;
          tw.x = cvtpk(vv[0], vv[1]);
          tw.y = cvtpk(vv[2], vv[3]);
          *(uint2*)(outt + (((size_t)bb2 * 16 + hh) * 64 + dk) * 512 + ll2) = tw;
        }
      } else {  // MODE 3
#pragma unroll
        for (int r = 0; r < 4; ++r) {
          int gm = gm0 + r;
          float v = vv[r] + bf2f(add0b[(size_t)gm * N + gn]) +
                    add1[(size_t)(gm & 511) * N + gn];
          outf[(size_t)gm * N + gn] = v;
        }
      }
    }
  }
}

// ---------------- fused attention: swapped-QK^T + swapped-PV ---------------
__global__ __launch_bounds__(512) void attn_kernel(const u16* __restrict__ q,
                                                   const u16* __restrict__ kv,
                                                   const u16* __restrict__ kvT,
                                                   u16* __restrict__ ctx) {
  __shared__ u16 sK[2][4096];   // [64 keys][64 dk], 128B rows, XOR swizzle
  __shared__ u16 sVT[2][4096];  // [64 dv][64 keys]
  __shared__ u16 sP[8192];      // Q staging (128x64), then per-wave P (16x64 each)

  int orig = (int)blockIdx.x;
  int r = (orig & 7) * 128 + (orig >> 3);
  int bh = r >> 2, qt = r & 3;
  int b = bh >> 4, h = bh & 15;
  int tid = threadIdx.x, w = tid >> 6, l = tid & 63;
  int c16 = l & 15, hi = l >> 4, g16 = hi * 16;
  int swzq = (c16 & 7) << 4;

  const u16* qbase = q + (size_t)bh * 32768 + (size_t)qt * 8192;
#pragma unroll
  for (int j = 0; j < 2; ++j) {
    int chunk = w * 2 + j;
    int lin = chunk * 1024 + l * 16;
    int row = lin >> 7;
    int cb = (lin & 127) ^ ((row & 7) << 4);
    gl2lds16(qbase + (size_t)row * 64 + (cb >> 1), (char*)sP + chunk * 1024);
  }
  {
    const u16* kb = kv + (size_t)bh * 32768;
    const u16* vb = kvT + (size_t)bh * 32768;
    int lin = w * 1024 + l * 16;
    int row = lin >> 7;
    int cb = (lin & 127) ^ ((row & 7) << 4);
    gl2lds16(kb + (size_t)row * 64 + (cb >> 1), (char*)sK[0] + w * 1024);
    gl2lds16(vb + (size_t)row * 512 + (cb >> 1), (char*)sVT[0] + w * 1024);
  }
  __syncthreads();

  const char* sQrow = (const char*)sP + (w * 16 + c16) * 128;
  bf16x8 qf0 = *(const bf16x8*)(sQrow + ((0 + g16) ^ swzq));
  bf16x8 qf1 = *(const bf16x8*)(sQrow + ((64 + g16) ^ swzq));

  char* sPw = (char*)sP + w * 2048;
  f32x4 of[4];
#pragma unroll
  for (int n = 0; n < 4; ++n) of[n] = (f32x4){0.f, 0.f, 0.f, 0.f};
  float m_run = -1e30f, l_run = 0.f;

  for (int c = 0; c < 8; ++c) {
    int cur = c & 1;
    if (c < 7) {
      const u16* kb = kv + (size_t)bh * 32768 + (size_t)(c + 1) * 4096;
      const u16* vb = kvT + (size_t)bh * 32768 + (c + 1) * 64;
      int lin = w * 1024 + l * 16;
      int row = lin >> 7;
      int cb = (lin & 127) ^ ((row & 7) << 4);
      gl2lds16(kb + (size_t)row * 64 + (cb >> 1), (char*)sK[cur ^ 1] + w * 1024);
      gl2lds16(vb + (size_t)row * 512 + (cb >> 1), (char*)sVT[cur ^ 1] + w * 1024);
    }
    const char* kbuf = (const char*)sK[cur];
    const char* vtbuf = (const char*)sVT[cur];

    f32x4 sf[4];
#pragma unroll
    for (int n = 0; n < 4; ++n) {
      const char* krow = kbuf + (n * 16 + c16) * 128;
      bf16x8 k0 = *(const bf16x8*)(krow + (g16 ^ swzq));
      bf16x8 k1 = *(const bf16x8*)(krow + ((64 + g16) ^ swzq));
      f32x4 z = (f32x4){0.f, 0.f, 0.f, 0.f};
      z = MFMA16(k0, qf0, z);
      z = MFMA16(k1, qf1, z);
      sf[n] = z;
    }

    float pmax = -1e30f;
#pragma unroll
    for (int n = 0; n < 4; ++n)
#pragma unroll
      for (int rr = 0; rr < 4; ++rr) {
        sf[n][rr] *= 0.125f;
        pmax = fmaxf(pmax, sf[n][rr]);
      }
    pmax = fmaxf(pmax, __shfl_xor(pmax, 16));
    pmax = fmaxf(pmax, __shfl_xor(pmax, 32));
    float mnew = fmaxf(m_run, pmax);
    float corr = __expf(m_run - mnew);
    float psum = 0.f;
#pragma unroll
    for (int n = 0; n < 4; ++n)
#pragma unroll
      for (int rr = 0; rr < 4; ++rr) {
        float p = __expf(sf[n][rr] - mnew);
        sf[n][rr] = p;
        psum += p;
      }
    psum += __shfl_xor(psum, 16);
    psum += __shfl_xor(psum, 32);
    l_run = l_run * corr + psum;
    m_run = mnew;
#pragma unroll
    for (int n = 0; n < 4; ++n)
#pragma unroll
      for (int rr = 0; rr < 4; ++rr) of[n][rr] *= corr;

#pragma unroll
    for (int n = 0; n < 4; ++n) {
      uint2 pw;
      pw.x = cvtpk(sf[n][0], sf[n][1]);
      pw.y = cvtpk(sf[n][2], sf[n][3]);
      *(uint2*)(sPw + c16 * 128 + ((n * 32 + hi * 8) ^ swzq)) = pw;
    }

    bf16x8 pf0 = *(const bf16x8*)(sPw + c16 * 128 + (g16 ^ swzq));
    bf16x8 pf1 = *(const bf16x8*)(sPw + c16 * 128 + ((64 + g16) ^ swzq));
#pragma unroll
    for (int n = 0; n < 4; ++n) {
      const char* vrow = vtbuf + (n * 16 + c16) * 128;
      bf16x8 v0 = *(const bf16x8*)(vrow + (g16 ^ swzq));
      bf16x8 v1 = *(const bf16x8*)(vrow + ((64 + g16) ^ swzq));
      of[n] = MFMA16(v0, pf0, of[n]);
      of[n] = MFMA16(v1, pf1, of[n]);
    }
    __syncthreads();
  }

  float inv = 1.0f / l_run;
  int grow = qt * 128 + w * 16 + c16;
  u16* obase = ctx + (size_t)(b * 512 + grow) * 1024 + h * 64;
#pragma unroll
  for (int n = 0; n < 4; ++n) {
    uint2 ow;
    ow.x = cvtpk(of[n][0] * inv, of[n][1] * inv);
    ow.y = cvtpk(of[n][2] * inv, of[n][3] * inv);
    *(uint2*)(obase + n * 16 + hi * 4) = ow;
  }
}

// ---------------- in-place LayerNorm over D=1024 ---------------------------
__global__ __launch_bounds__(256) void ln_kernel(float* __restrict__ x,
                                                 const float* __restrict__ gamma,
                                                 const float* __restrict__ beta) {
  __shared__ float red[4];
  __shared__ float red2[4];
  int row = blockIdx.x, tid = threadIdx.x;
  float4 v = *(float4*)(x + (size_t)row * 1024 + tid * 4);
  float s = v.x + v.y + v.z + v.w;
#pragma unroll
  for (int d = 1; d < 64; d <<= 1) s += __shfl_xor(s, d);
  if ((tid & 63) == 0) red[tid >> 6] = s;
  __syncthreads();
  float mu = (red[0] + red[1] + red[2] + red[3]) * (1.0f / 1024.0f);
  float d0 = v.x - mu, d1 = v.y - mu, d2 = v.z - mu, d3 = v.w - mu;
  float qq = d0 * d0 + d1 * d1 + d2 * d2 + d3 * d3;
#pragma unroll
  for (int d = 1; d < 64; d <<= 1) qq += __shfl_xor(qq, d);
  if ((tid & 63) == 0) red2[tid >> 6] = qq;
  __syncthreads();
  float var = (red2[0] + red2[1] + red2[2] + red2[3]) * (1.0f / 1024.0f);
  float rstd = rsqrtf(var + 1e-6f);
  float4 g = *(const float4*)(gamma + tid * 4);
  float4 bb = *(const float4*)(beta + tid * 4);
  v.x = g.x * d0 * rstd + bb.x;
  v.y = g.y * d1 * rstd + bb.y;
  v.z = g.z * d2 * rstd + bb.z;
  v.w = g.w * d3 * rstd + bb.w;
  *(float4*)(x + (size_t)row * 1024 + tid * 4) = v;
}

extern "C" void kernel_launch(void* const* d_in, const int* in_sizes, int n_in,
                              void* d_out, int out_size, void* d_ws, size_t ws_size,
                              hipStream_t stream) {
  (void)in_sizes; (void)n_in; (void)out_size; (void)ws_size;
  const float* v_in  = (const float*)d_in[0];
  const float* s_in  = (const float*)d_in[1];
  const float* W_lv  = (const float*)d_in[2];
  const float* b_lv  = (const float*)d_in[3];
  const float* W_ls  = (const float*)d_in[4];
  const float* b_ls  = (const float*)d_in[5];
  const float* pos_v = (const float*)d_in[6];
  // d_in[7] = pos_s (unused), d_in[10]/[11] = W_k/b_k (discarded in ref)
  const float* W_q   = (const float*)d_in[8];
  const float* b_q   = (const float*)d_in[9];
  const float* W_v   = (const float*)d_in[12];
  const float* b_v   = (const float*)d_in[13];
  const float* W_p   = (const float*)d_in[14];
  const float* b_p   = (const float*)d_in[15];
  const float* gamma = (const float*)d_in[16];
  const float* beta  = (const float*)d_in[17];
  float* out = (float*)d_out;

  char* ws = (char*)d_ws;
  size_t off = 0;
  auto alloc = [&](size_t bytes) {
    char* p = ws + off;
    off += (bytes + 255) & ~(size_t)255;
    return p;
  };
  u16* v_bf     = (u16*)alloc(33554432);   // [8192][2048] bf16
  u16* s_bf     = (u16*)alloc(12582912);   // [8192][768]
  u16* Wlv_t    = (u16*)alloc(4194304);    // [1024][2048] bf16
  u16* Wls_t    = (u16*)alloc(1572864);    // [1024][768]
  u16* Wq_t     = (u16*)alloc(2097152);    // [1024][1024]
  u16* Wv_t     = (u16*)alloc(2097152);
  u16* Wp_t     = (u16*)alloc(2097152);
  u16* vproj_bf = (u16*)alloc(16777216);   // [8192][1024] (also the residual, bf16)
  u16* sproj_bf = (u16*)alloc(16777216);
  u16* q_bf     = (u16*)alloc(16777216);   // [BH][512][64]
  u16* vs_bf    = (u16*)alloc(16777216);   // [BH][512][64]
  u16* vsT_bf   = (u16*)alloc(16777216);   // [BH][64][512]
  u16* ctx_bf   = (u16*)alloc(16777216);   // [8192][1024]

  cvt_f32_bf16<<<8192, 256, 0, stream>>>(v_in, v_bf, 2097152);
  cvt_f32_bf16<<<3072, 256, 0, stream>>>(s_in, s_bf, 786432);
  wt_cvt_t<<<512, 256, 0, stream>>>(W_lv, Wlv_t, 2048, 1024);
  wt_cvt_t<<<192, 256, 0, stream>>>(W_ls, Wls_t, 768, 1024);
  wt_cvt_t<<<256, 256, 0, stream>>>(W_q, Wq_t, 1024, 1024);
  wt_cvt_t<<<256, 256, 0, stream>>>(W_v, Wv_t, 1024, 1024);
  wt_cvt_t<<<256, 256, 0, stream>>>(W_p, Wp_t, 1024, 1024);

  // v-proj + s-proj (bf16 A via gl2lds, counted-vmcnt double-buffered pipeline)
  gemm_bf16<0><<<512, 512, 0, stream>>>(v_bf, Wlv_t, b_lv, vproj_bf, nullptr,
                                        nullptr, nullptr, nullptr, 8192, 1024, 2048);
  gemm_bf16<0><<<512, 512, 0, stream>>>(s_bf, Wls_t, b_ls, sproj_bf, nullptr,
                                        nullptr, nullptr, nullptr, 8192, 1024, 768);
  // q-proj
  gemm_bf16<2><<<512, 512, 0, stream>>>(vproj_bf, Wq_t, b_q, q_bf, nullptr,
                                        nullptr, nullptr, nullptr, 8192, 1024, 1024);
  // vs-proj with fused transpose (writes vs and vs^T)
  gemm_bf16<4><<<512, 512, 0, stream>>>(sproj_bf, Wv_t, b_v, vs_bf, nullptr,
                                        vsT_bf, nullptr, nullptr, 8192, 1024, 1024);
  attn_kernel<<<1024, 512, 0, stream>>>(q_bf, vs_bf, vsT_bf, ctx_bf);
  // out-proj + residual(bf16) + pos_v
  gemm_bf16<3><<<512, 512, 0, stream>>>(ctx_bf, Wp_t, b_p, nullptr, out,
                                        nullptr, vproj_bf, pos_v, 8192, 1024, 1024);
  ln_kernel<<<8192, 256, 0, stream>>>(out, gamma, beta);
}